// Round 9
// baseline (406.486 us; speedup 1.0000x reference)
//
#include <hip/hip_runtime.h>
#include <hip/hip_bf16.h>

// B=4, C=256, C8=32 (=Dn), H=W=64, N=4096. fp32 I/O; bf16 internal.
#define Bn 4
#define Cn 256
#define Dn 32
#define Nn 4096

typedef __bf16 bf16x8 __attribute__((ext_vector_type(8)));
typedef float f32x4 __attribute__((ext_vector_type(4)));

__device__ __forceinline__ float bf2f(unsigned short u) {
  unsigned int v = ((unsigned int)u) << 16;
  return __builtin_bit_cast(float, v);
}
__device__ __forceinline__ unsigned short f2bf(float f) {
  unsigned int v = __builtin_bit_cast(unsigned int, f);
  v += 0x7FFFu + ((v >> 16) & 1u);  // RNE
  return (unsigned short)(v >> 16);
}
// hardware packed cvt: 2 fp32 -> 2 bf16 (v_cvt_pk_bf16_f32)
__device__ __forceinline__ unsigned int pk2(float a, float b) {
  union { __hip_bfloat162 h; unsigned int u; } x;
  x.h = __float22bfloat162_rn(make_float2(a, b));
  return x.u;
}
__device__ __forceinline__ bf16x8 ldfrag(const unsigned short* p) {
  return __builtin_bit_cast(bf16x8, *(const uint4*)p);
}
__device__ __forceinline__ uint4 pack8(const float* p) {
  float4 a = *(const float4*)p;
  float4 b = *(const float4*)(p + 4);
  union { unsigned int u2[4]; uint4 u; } x;
  x.u2[0] = pk2(a.x, a.y); x.u2[1] = pk2(a.z, a.w);
  x.u2[2] = pk2(b.x, b.y); x.u2[3] = pk2(b.z, b.w);
  return x.u;
}
__device__ __forceinline__ bf16x8 ldfrag_f32(const float* p) {
  float4 a = *(const float4*)p;
  float4 b = *(const float4*)(p + 4);
  union { unsigned int u2[4]; bf16x8 v; } x;
  x.u2[0] = pk2(a.x, a.y); x.u2[1] = pk2(a.z, a.w);
  x.u2[2] = pk2(b.x, b.y); x.u2[3] = pk2(b.z, b.w);
  return x.v;
}
// async global->LDS, 16 B per lane
__device__ __forceinline__ void async16(unsigned short* lds, const unsigned short* g) {
  __builtin_amdgcn_global_load_lds(
      (const __attribute__((address_space(1))) unsigned int*)g,
      (__attribute__((address_space(3))) unsigned int*)lds, 16, 0, 0);
}

// ---------------------------------------------------------------------------
// Kernel 1: qkprep (unchanged from R7). Blocks 0..511: LDS-free Q/K proj GEMM.
// Blocks 512..1023: bf16 copy pre -> preBf. Blocks 1024..1031: Wv -> WvBf.
// Qt scaled by log2(e) so flash softmax uses raw exp2.
// ---------------------------------------------------------------------------
__global__ __launch_bounds__(256) void qkprep(
    const float* __restrict__ pre, const float* __restrict__ post,
    const float* __restrict__ Wq, const float* __restrict__ bq,
    const float* __restrict__ Wk, const float* __restrict__ bk,
    const float* __restrict__ Wv,
    unsigned short* __restrict__ Qt, unsigned short* __restrict__ Kt,
    unsigned short* __restrict__ preBf, unsigned short* __restrict__ WvBf)
{
  const int blk = blockIdx.x, tid = threadIdx.x;
  if (blk >= 512) {
    if (blk < 1024) {
      size_t base = ((size_t)(blk - 512) * 256 + tid) * 32;
#pragma unroll
      for (int u = 0; u < 4; u++)
        *(uint4*)(preBf + base + u * 8) = pack8(pre + base + u * 8);
    } else {
      size_t base = ((size_t)(blk - 1024) * 256 + tid) * 32;
#pragma unroll
      for (int u = 0; u < 4; u++)
        *(uint4*)(WvBf + base + u * 8) = pack8(Wv + base + u * 8);
    }
    return;
  }
  const int lane = tid & 63, w = tid >> 6;
  const int quad = lane >> 4, n16 = lane & 15;
  const int b = blk >> 7;
  const int i0 = (blk & 127) << 5;
  const int isub = w & 1, dh = w >> 1;
  const int i = i0 + isub * 16 + n16;

  const f32x4 zz = {0.f, 0.f, 0.f, 0.f};
  f32x4 aq = zz, ak = zz;
  const float* postB = post + (size_t)b * Cn * Nn + i;
  const float* preB  = pre  + (size_t)b * Cn * Nn + i;

#pragma unroll
  for (int kc = 0; kc < 8; kc++) {
    const int c0 = kc * 32 + quad * 8;
    const float* pp = postB + (size_t)c0 * Nn;
    const float* pr = preB + (size_t)c0 * Nn;
    union { unsigned int u2[4]; bf16x8 v; } bp, bq8;
#pragma unroll
    for (int e2 = 0; e2 < 4; e2++) {
      float p0 = pp[(size_t)(2 * e2) * Nn], p1 = pp[(size_t)(2 * e2 + 1) * Nn];
      float r0 = pr[(size_t)(2 * e2) * Nn], r1 = pr[(size_t)(2 * e2 + 1) * Nn];
      bp.u2[e2] = pk2(p0, p1);
      bq8.u2[e2] = pk2(r0, r1);
    }
    bf16x8 awq = ldfrag_f32(Wq + (size_t)(dh * 16 + n16) * Cn + kc * 32 + quad * 8);
    bf16x8 awk = ldfrag_f32(Wk + (size_t)(dh * 16 + n16) * Cn + kc * 32 + quad * 8);
    aq = __builtin_amdgcn_mfma_f32_16x16x32_bf16(awq, bp.v, aq, 0, 0, 0);
    ak = __builtin_amdgcn_mfma_f32_16x16x32_bf16(awk, bq8.v, ak, 0, 0, 0);
  }
  const float LOG2E = 1.44269504f;
  union { unsigned short s[4]; uint2 u; } oq, ok;
#pragma unroll
  for (int r = 0; r < 4; r++) {
    int d = dh * 16 + quad * 4 + r;
    oq.s[r] = f2bf((aq[r] + bq[d]) * LOG2E);
    ok.s[r] = f2bf(ak[r] + bk[d]);
  }
  *(uint2*)(Qt + ((size_t)b * Nn + i) * Dn + dh * 16 + quad * 4) = oq.u;
  *(uint2*)(Kt + ((size_t)b * Nn + i) * Dn + dh * 16 + quad * 4) = ok.u;
}

// ---------------------------------------------------------------------------
// Kernel 2: flash attention + fused last-finisher combine.
// Grid 1024 = 4b x 64 it(64 i) x 4 js; 128 thr = 2 waves, c-split (wave w
// owns c in [w*128, w*128+128), all 64 i). Single-buffered sX (3 blocks/CU).
// After partial store: device-scope counter; 4th block of the (b,it) group
// merges partials (L2-warm), normalizes, O = Wv*Ubar + bv, out = g*O + post.
// ---------------------------------------------------------------------------
__global__ __launch_bounds__(128) void flash_fused(
    const unsigned short* __restrict__ Qt, const unsigned short* __restrict__ Kt,
    const unsigned short* __restrict__ preBf,
    const unsigned short* __restrict__ WvBf, const float* __restrict__ bv,
    const float* __restrict__ post, const float* __restrict__ gamma,
    unsigned short* __restrict__ Opart, float* __restrict__ Lpart,
    int* __restrict__ cnt, float* __restrict__ out)
{
  __shared__ __align__(16) unsigned short smem[20992];  // sX 16384 | Pl 64x72
  __shared__ float sL[64];
  __shared__ int sFlag;
  unsigned short* sX = smem;
  unsigned short* Pl = smem + 16384;     // [64][72]

  const int tid = threadIdx.x;
  const int lane = tid & 63, w = tid >> 6;
  const int quad = lane >> 4, n16 = lane & 15;
  const int b = blockIdx.x >> 8;
  const int js = (blockIdx.x >> 6) & 3;
  const int it = blockIdx.x & 63;
  const int i0 = it * 64;
  const int jbase = js * 1024;

  // Q B-frags for this wave's two 16-i subtiles (S^T: B n=i, k=d)
  bf16x8 qf[2];
#pragma unroll
  for (int s2 = 0; s2 < 2; s2++)
    qf[s2] = ldfrag(Qt + ((size_t)b * Nn + i0 + w * 32 + s2 * 16 + n16) * Dn + quad * 8);

  const f32x4 zz = {0.f, 0.f, 0.f, 0.f};
  f32x4 acc[4][8];
#pragma unroll
  for (int sub = 0; sub < 4; sub++)
#pragma unroll
    for (int ct = 0; ct < 8; ct++) acc[sub][ct] = zz;
  float lrow[2] = {0.f, 0.f};

  const size_t laneoff = (size_t)(lane >> 3) * Nn + (size_t)(((lane & 7) ^ (lane >> 3)) << 3);
  const unsigned short* preB = preBf + (size_t)b * Cn * Nn + laneoff;
  const int xsw = n16 & 7;
  const int xoff0 = (quad ^ xsw) << 3;
  const int xoff1 = ((4 + quad) ^ xsw) << 3;

  for (int t = 0; t < 16; ++t) {
    const int j0 = jbase + t * 64;
    __syncthreads();                      // sX(t-1) fully consumed
    // async stage pre tile (XOR col swizzle)
#pragma unroll
    for (int k = 0; k < 16; k++) {
      const int rb = (k * 2 + w) * 8;
      async16(sX + rb * 64 + (lane << 3), preB + (size_t)rb * Nn + j0);
    }
    // S^T = K Q^T for this wave's 32 i; K b128 direct from L2-resident Kt
    {
      f32x4 sc[2][4];
#pragma unroll
      for (int jt = 0; jt < 4; jt++) {
        bf16x8 akf = ldfrag(Kt + ((size_t)b * Nn + j0 + jt * 16 + n16) * Dn + quad * 8);
        sc[0][jt] = __builtin_amdgcn_mfma_f32_16x16x32_bf16(akf, qf[0], zz, 0, 0, 0);
        sc[1][jt] = __builtin_amdgcn_mfma_f32_16x16x32_bf16(akf, qf[1], zz, 0, 0, 0);
      }
#pragma unroll
      for (int s2 = 0; s2 < 2; s2++) {
        const int irow = w * 32 + s2 * 16 + n16;
        float ps = 0.f;
#pragma unroll
        for (int jt = 0; jt < 4; jt++) {
          float p0 = exp2f(fminf(sc[s2][jt][0], 101.f));
          float p1 = exp2f(fminf(sc[s2][jt][1], 101.f));
          float p2 = exp2f(fminf(sc[s2][jt][2], 101.f));
          float p3 = exp2f(fminf(sc[s2][jt][3], 101.f));
          ps += (p0 + p1) + (p2 + p3);
          union { unsigned int u2[2]; uint2 u; } pk;
          pk.u2[0] = pk2(p0, p1);
          pk.u2[1] = pk2(p2, p3);
          *(uint2*)&Pl[(size_t)irow * 72 + jt * 16 + quad * 4] = pk.u;
        }
        ps += __shfl_xor(ps, 16);
        ps += __shfl_xor(ps, 32);
        lrow[s2] += ps;
      }
    }
    __syncthreads();                      // DMA drained + Pl visible

    // PV(t): U[c][i] += pre[c][j] P^T[j][i], 16x16x32 (k=32 j)
#pragma unroll
    for (int kc = 0; kc < 2; kc++) {
      const int xo = kc ? xoff1 : xoff0;
      bf16x8 pB[4];
#pragma unroll
      for (int sub = 0; sub < 4; sub++)
        pB[sub] = ldfrag(&Pl[(size_t)(sub * 16 + n16) * 72 + kc * 32 + quad * 8]);
#pragma unroll
      for (int ct = 0; ct < 8; ct++) {
        const int crow = w * 128 + ct * 16 + n16;
        bf16x8 av = ldfrag(&sX[crow * 64 + xo]);
        acc[0][ct] = __builtin_amdgcn_mfma_f32_16x16x32_bf16(av, pB[0], acc[0][ct], 0, 0, 0);
        acc[1][ct] = __builtin_amdgcn_mfma_f32_16x16x32_bf16(av, pB[1], acc[1][ct], 0, 0, 0);
        acc[2][ct] = __builtin_amdgcn_mfma_f32_16x16x32_bf16(av, pB[2], acc[2][ct], 0, 0, 0);
        acc[3][ct] = __builtin_amdgcn_mfma_f32_16x16x32_bf16(av, pB[3], acc[3][ct], 0, 0, 0);
      }
    }
  }

  // ---- partial store: U bf16 [js*4+b][i][c], l fp32 ----
  const size_t pbase = (size_t)(js * 4 + b) * Nn;
  if (quad == 0) {
    Lpart[pbase + i0 + w * 32 + n16] = lrow[0];
    Lpart[pbase + i0 + w * 32 + 16 + n16] = lrow[1];
  }
#pragma unroll
  for (int sub = 0; sub < 4; sub++) {
    const int i = i0 + sub * 16 + n16;
#pragma unroll
    for (int ct = 0; ct < 8; ct++) {
      union { unsigned int u2[2]; uint2 u; } pk;
      pk.u2[0] = pk2(acc[sub][ct][0], acc[sub][ct][1]);
      pk.u2[1] = pk2(acc[sub][ct][2], acc[sub][ct][3]);
      *(uint2*)(Opart + (pbase + i) * 256 + w * 128 + ct * 16 + quad * 4) = pk.u;
    }
  }

  // ---- last-finisher combine ----
  __threadfence();                         // release partials (device scope)
  if (tid == 0) sFlag = atomicAdd(&cnt[b * 64 + it], 1);
  __syncthreads();
  if (sFlag != 3) return;
  __threadfence();                         // acquire

  if (tid < 64) {
    float l = 0.f;
#pragma unroll
    for (int j4 = 0; j4 < 4; j4++) l += Lpart[(size_t)(j4 * 4 + b) * Nn + i0 + tid];
    sL[tid] = 1.f / l;
  }
  __syncthreads();

  // merge 4 partials -> sU[64 i][264 c'] bf16 (overlay on smem)
  unsigned short* sU = smem;
#pragma unroll
  for (int p = 0; p < 16; p++) {
    const int task = tid + p * 128;        // 2048 = 64 i x 32 c-octets
    const int il = task >> 5, c8 = (task & 31) << 3;
    const float inv = sL[il];
    float a[8] = {0.f, 0.f, 0.f, 0.f, 0.f, 0.f, 0.f, 0.f};
#pragma unroll
    for (int j4 = 0; j4 < 4; j4++) {
      uint4 uu = *(const uint4*)(Opart + ((size_t)(j4 * 4 + b) * Nn + i0 + il) * 256 + c8);
      const unsigned short* us = (const unsigned short*)&uu;
#pragma unroll
      for (int e = 0; e < 8; e++) a[e] += bf2f(us[e]);
    }
    union { unsigned int u2[4]; uint4 u; } pk;
#pragma unroll
    for (int e2 = 0; e2 < 4; e2++) pk.u2[e2] = pk2(a[2 * e2] * inv, a[2 * e2 + 1] * inv);
    *(uint4*)&sU[(size_t)il * 264 + c8] = pk.u;
  }
  __syncthreads();

  // O = Wv * Ubar + bv; out = g*O + post. Wave w handles ct2 = w*8..w*8+7.
  const float g = gamma[0];
#pragma unroll
  for (int sub = 0; sub < 4; sub++) {
    bf16x8 ub[8];
#pragma unroll
    for (int kc = 0; kc < 8; kc++)
      ub[kc] = ldfrag(&sU[(size_t)(sub * 16 + n16) * 264 + kc * 32 + quad * 8]);
#pragma unroll
    for (int e = 0; e < 8; e++) {
      const int ct2 = w * 8 + e;
      f32x4 o = zz;
#pragma unroll
      for (int kc = 0; kc < 8; kc++) {
        bf16x8 awv = ldfrag(WvBf + (size_t)(ct2 * 16 + n16) * Cn + kc * 32 + quad * 8);
        o = __builtin_amdgcn_mfma_f32_16x16x32_bf16(awv, ub[kc], o, 0, 0, 0);
      }
#pragma unroll
      for (int r = 0; r < 4; r++) {
        const int c = ct2 * 16 + quad * 4 + r;
        const size_t addr = ((size_t)b * Cn + c) * Nn + i0 + sub * 16 + n16;
        out[addr] = g * (o[r] + bv[c]) + post[addr];
      }
    }
  }
}

extern "C" void kernel_launch(void* const* d_in, const int* in_sizes, int n_in,
                              void* d_out, int out_size, void* d_ws, size_t ws_size,
                              hipStream_t stream) {
  const float* pre   = (const float*)d_in[0];
  const float* post  = (const float*)d_in[1];
  const float* Wq    = (const float*)d_in[2];
  const float* bq    = (const float*)d_in[3];
  const float* Wk    = (const float*)d_in[4];
  const float* bk    = (const float*)d_in[5];
  const float* Wv    = (const float*)d_in[6];
  const float* bv    = (const float*)d_in[7];
  const float* gamma = (const float*)d_in[8];
  float* out = (float*)d_out;

  unsigned short* ws = (unsigned short*)d_ws;
  unsigned short* Qt    = ws;                                   // 512K sh
  unsigned short* Kt    = Qt + (size_t)Bn * Nn * Dn;            // 512K sh
  unsigned short* preBf = Kt + (size_t)Bn * Nn * Dn;            // 4M sh
  unsigned short* WvBf  = preBf + (size_t)Bn * Cn * Nn;         // 64K sh
  float* Lpart = (float*)(WvBf + Cn * Cn);                      // 64K fl
  unsigned short* Opart = (unsigned short*)(Lpart + 4 * Bn * Nn);  // 16.7M sh
  int* cnt = (int*)(Opart + (size_t)4 * Bn * Nn * Cn);          // 256 int

  hipMemsetAsync(cnt, 0, 256 * sizeof(int), stream);
  qkprep<<<1032, 256, 0, stream>>>(pre, post, Wq, bq, Wk, bk, Wv,
                                   Qt, Kt, preBf, WvBf);
  flash_fused<<<1024, 128, 0, stream>>>(Qt, Kt, preBf, WvBf, bv, post, gamma,
                                        Opart, Lpart, cnt, out);
}

// Round 10
// 202.071 us; speedup vs baseline: 2.0116x; 2.0116x over previous
//
#include <hip/hip_runtime.h>
#include <hip/hip_bf16.h>

// B=4, C=256, C8=32 (=Dn), H=W=64, N=4096. fp32 I/O; bf16 internal.
#define Bn 4
#define Cn 256
#define Dn 32
#define Nn 4096

typedef __bf16 bf16x8 __attribute__((ext_vector_type(8)));
typedef float f32x4 __attribute__((ext_vector_type(4)));

__device__ __forceinline__ float bf2f(unsigned short u) {
  unsigned int v = ((unsigned int)u) << 16;
  return __builtin_bit_cast(float, v);
}
__device__ __forceinline__ unsigned short f2bf(float f) {
  unsigned int v = __builtin_bit_cast(unsigned int, f);
  v += 0x7FFFu + ((v >> 16) & 1u);  // RNE
  return (unsigned short)(v >> 16);
}
// hardware packed cvt: 2 fp32 -> 2 bf16 (v_cvt_pk_bf16_f32)
__device__ __forceinline__ unsigned int pk2(float a, float b) {
  union { __hip_bfloat162 h; unsigned int u; } x;
  x.h = __float22bfloat162_rn(make_float2(a, b));
  return x.u;
}
__device__ __forceinline__ bf16x8 ldfrag(const unsigned short* p) {
  return __builtin_bit_cast(bf16x8, *(const uint4*)p);
}
__device__ __forceinline__ uint4 pack8(const float* p) {
  float4 a = *(const float4*)p;
  float4 b = *(const float4*)(p + 4);
  union { unsigned int u2[4]; uint4 u; } x;
  x.u2[0] = pk2(a.x, a.y); x.u2[1] = pk2(a.z, a.w);
  x.u2[2] = pk2(b.x, b.y); x.u2[3] = pk2(b.z, b.w);
  return x.u;
}
__device__ __forceinline__ bf16x8 ldfrag_f32(const float* p) {
  float4 a = *(const float4*)p;
  float4 b = *(const float4*)(p + 4);
  union { unsigned int u2[4]; bf16x8 v; } x;
  x.u2[0] = pk2(a.x, a.y); x.u2[1] = pk2(a.z, a.w);
  x.u2[2] = pk2(b.x, b.y); x.u2[3] = pk2(b.z, b.w);
  return x.v;
}
// async global->LDS, 16 B per lane (lds dest = wave-uniform base + lane*16)
__device__ __forceinline__ void async16(unsigned short* lds, const unsigned short* g) {
  __builtin_amdgcn_global_load_lds(
      (const __attribute__((address_space(1))) unsigned int*)g,
      (__attribute__((address_space(3))) unsigned int*)lds, 16, 0, 0);
}

// ---------------------------------------------------------------------------
// Kernel 1: qkprep (R7). Blocks 0..511: LDS-free Q/K proj GEMM. Blocks
// 512..1023: bf16 copy pre -> preBf. Blocks 1024..1031: Wv -> WvBf.
// Qt scaled by log2(e) so flash softmax uses raw exp2.
// ---------------------------------------------------------------------------
__global__ __launch_bounds__(256) void qkprep(
    const float* __restrict__ pre, const float* __restrict__ post,
    const float* __restrict__ Wq, const float* __restrict__ bq,
    const float* __restrict__ Wk, const float* __restrict__ bk,
    const float* __restrict__ Wv,
    unsigned short* __restrict__ Qt, unsigned short* __restrict__ Kt,
    unsigned short* __restrict__ preBf, unsigned short* __restrict__ WvBf)
{
  const int blk = blockIdx.x, tid = threadIdx.x;
  if (blk >= 512) {
    if (blk < 1024) {
      size_t base = ((size_t)(blk - 512) * 256 + tid) * 32;
#pragma unroll
      for (int u = 0; u < 4; u++)
        *(uint4*)(preBf + base + u * 8) = pack8(pre + base + u * 8);
    } else {
      size_t base = ((size_t)(blk - 1024) * 256 + tid) * 32;
#pragma unroll
      for (int u = 0; u < 4; u++)
        *(uint4*)(WvBf + base + u * 8) = pack8(Wv + base + u * 8);
    }
    return;
  }
  const int lane = tid & 63, w = tid >> 6;
  const int quad = lane >> 4, n16 = lane & 15;
  const int b = blk >> 7;
  const int i0 = (blk & 127) << 5;
  const int isub = w & 1, dh = w >> 1;
  const int i = i0 + isub * 16 + n16;

  const f32x4 zz = {0.f, 0.f, 0.f, 0.f};
  f32x4 aq = zz, ak = zz;
  const float* postB = post + (size_t)b * Cn * Nn + i;
  const float* preB  = pre  + (size_t)b * Cn * Nn + i;

#pragma unroll
  for (int kc = 0; kc < 8; kc++) {
    const int c0 = kc * 32 + quad * 8;
    const float* pp = postB + (size_t)c0 * Nn;
    const float* pr = preB + (size_t)c0 * Nn;
    union { unsigned int u2[4]; bf16x8 v; } bp, bq8;
#pragma unroll
    for (int e2 = 0; e2 < 4; e2++) {
      float p0 = pp[(size_t)(2 * e2) * Nn], p1 = pp[(size_t)(2 * e2 + 1) * Nn];
      float r0 = pr[(size_t)(2 * e2) * Nn], r1 = pr[(size_t)(2 * e2 + 1) * Nn];
      bp.u2[e2] = pk2(p0, p1);
      bq8.u2[e2] = pk2(r0, r1);
    }
    bf16x8 awq = ldfrag_f32(Wq + (size_t)(dh * 16 + n16) * Cn + kc * 32 + quad * 8);
    bf16x8 awk = ldfrag_f32(Wk + (size_t)(dh * 16 + n16) * Cn + kc * 32 + quad * 8);
    aq = __builtin_amdgcn_mfma_f32_16x16x32_bf16(awq, bp.v, aq, 0, 0, 0);
    ak = __builtin_amdgcn_mfma_f32_16x16x32_bf16(awk, bq8.v, ak, 0, 0, 0);
  }
  const float LOG2E = 1.44269504f;
  union { unsigned short s[4]; uint2 u; } oq, ok;
#pragma unroll
  for (int r = 0; r < 4; r++) {
    int d = dh * 16 + quad * 4 + r;
    oq.s[r] = f2bf((aq[r] + bq[d]) * LOG2E);
    ok.s[r] = f2bf(ak[r] + bk[d]);
  }
  *(uint2*)(Qt + ((size_t)b * Nn + i) * Dn + dh * 16 + quad * 4) = oq.u;
  *(uint2*)(Kt + ((size_t)b * Nn + i) * Dn + dh * 16 + quad * 4) = ok.u;
}

// ---------------------------------------------------------------------------
// Kernel 2: flash attention v6. Grid 1024 = 4b x 64 it(64 i) x 4 js;
// 256 thr = 4 waves. Wave w: S^T/softmax for i-subtile w (16 i), PV for
// c-range [w*64, w*64+64) x all 64 i (acc 16 f32x4 = 64 VGPR).
// Single-buffered sX (41.2 KB LDS -> 3 blocks/CU = 12 waves/CU).
// ---------------------------------------------------------------------------
__global__ __launch_bounds__(256) void flash_attn(
    const unsigned short* __restrict__ Qt, const unsigned short* __restrict__ Kt,
    const unsigned short* __restrict__ preBf,
    unsigned short* __restrict__ Opart, float* __restrict__ Lpart)
{
  __shared__ __align__(16) unsigned short sX[256 * 64];  // 32 KB
  __shared__ __align__(16) unsigned short Pl[64 * 72];   // 9.2 KB

  const int tid = threadIdx.x;
  const int lane = tid & 63, w = tid >> 6;
  const int quad = lane >> 4, n16 = lane & 15;
  const int b = blockIdx.x >> 8;
  const int js = (blockIdx.x >> 6) & 3;
  const int it = blockIdx.x & 63;
  const int i0 = it * 64;
  const int jbase = js * 1024;

  // Q B-frag for wave's own 16-i subtile (S^T: B n=i, k=d)
  const bf16x8 qf = ldfrag(Qt + ((size_t)b * Nn + i0 + w * 16 + n16) * Dn + quad * 8);

  const f32x4 zz = {0.f, 0.f, 0.f, 0.f};
  f32x4 acc[4][4];                       // [i-sub][c-tile within wave's 64 c]
#pragma unroll
  for (int sub = 0; sub < 4; sub++)
#pragma unroll
    for (int ct = 0; ct < 4; ct++) acc[sub][ct] = zz;
  float lrow = 0.f;                      // softmax denom, col i = n16 (dup x4)

  const size_t laneoff = (size_t)(lane >> 3) * Nn + (size_t)(((lane & 7) ^ (lane >> 3)) << 3);
  const unsigned short* preB = preBf + (size_t)b * Cn * Nn + laneoff;
  const int xsw = n16 & 7;
  const int xoff0 = (quad ^ xsw) << 3;
  const int xoff1 = ((4 + quad) ^ xsw) << 3;

  for (int t = 0; t < 16; ++t) {
    const int j0 = jbase + t * 64;
    __syncthreads();                     // sX(t-1)/Pl(t-1) fully consumed
    // async stage pre tile 256c x 64j (XOR col swizzle), 8 x 16B per lane
#pragma unroll
    for (int k = 0; k < 8; k++) {
      const int rb = (k * 4 + w) * 8;
      async16(sX + rb * 64 + (lane << 3), preB + (size_t)rb * Nn + j0);
    }
    // S^T = K Q^T for wave's 16 i; K b128 direct from L2-resident Kt
    {
      f32x4 sc[4];
#pragma unroll
      for (int jt = 0; jt < 4; jt++) {
        bf16x8 akf = ldfrag(Kt + ((size_t)b * Nn + j0 + jt * 16 + n16) * Dn + quad * 8);
        sc[jt] = __builtin_amdgcn_mfma_f32_16x16x32_bf16(akf, qf, zz, 0, 0, 0);
      }
      float ps = 0.f;
#pragma unroll
      for (int jt = 0; jt < 4; jt++) {
        float p0 = exp2f(fminf(sc[jt][0], 101.f));
        float p1 = exp2f(fminf(sc[jt][1], 101.f));
        float p2 = exp2f(fminf(sc[jt][2], 101.f));
        float p3 = exp2f(fminf(sc[jt][3], 101.f));
        ps += (p0 + p1) + (p2 + p3);
        union { unsigned int u2[2]; uint2 u; } pk;
        pk.u2[0] = pk2(p0, p1);
        pk.u2[1] = pk2(p2, p3);
        // Pl[i][j], i = w*16+n16, j = jt*16+quad*4..+3
        *(uint2*)&Pl[(size_t)(w * 16 + n16) * 72 + jt * 16 + quad * 4] = pk.u;
      }
      ps += __shfl_xor(ps, 16);
      ps += __shfl_xor(ps, 32);
      lrow += ps;
    }
    __syncthreads();                     // DMA drained + Pl visible

    // PV(t): U[c][i] += pre[c][j] P^T[j][i], 16x16x32 (k = 32 j)
#pragma unroll
    for (int kc = 0; kc < 2; kc++) {
      const int xo = kc ? xoff1 : xoff0;
      bf16x8 pB[4];
#pragma unroll
      for (int sub = 0; sub < 4; sub++)
        pB[sub] = ldfrag(&Pl[(size_t)(sub * 16 + n16) * 72 + kc * 32 + quad * 8]);
#pragma unroll
      for (int ct = 0; ct < 4; ct++) {
        const int crow = w * 64 + ct * 16 + n16;
        bf16x8 av = ldfrag(&sX[crow * 64 + xo]);
        acc[0][ct] = __builtin_amdgcn_mfma_f32_16x16x32_bf16(av, pB[0], acc[0][ct], 0, 0, 0);
        acc[1][ct] = __builtin_amdgcn_mfma_f32_16x16x32_bf16(av, pB[1], acc[1][ct], 0, 0, 0);
        acc[2][ct] = __builtin_amdgcn_mfma_f32_16x16x32_bf16(av, pB[2], acc[2][ct], 0, 0, 0);
        acc[3][ct] = __builtin_amdgcn_mfma_f32_16x16x32_bf16(av, pB[3], acc[3][ct], 0, 0, 0);
      }
    }
  }

  // partial store: U bf16 [js*4+b][i][c], l fp32 [js*4+b][i]
  const size_t pbase = (size_t)(js * 4 + b) * Nn;
  if (quad == 0) Lpart[pbase + i0 + w * 16 + n16] = lrow;
#pragma unroll
  for (int sub = 0; sub < 4; sub++) {
    const int i = i0 + sub * 16 + n16;
#pragma unroll
    for (int ct = 0; ct < 4; ct++) {
      union { unsigned int u2[2]; uint2 u; } pk;
      pk.u2[0] = pk2(acc[sub][ct][0], acc[sub][ct][1]);
      pk.u2[1] = pk2(acc[sub][ct][2], acc[sub][ct][3]);
      *(uint2*)(Opart + (pbase + i) * 256 + w * 64 + ct * 16 + quad * 4) = pk.u;
    }
  }
}

// ---------------------------------------------------------------------------
// Kernel 3: merge 4 js-partials, normalize, O = Wv*Ubar + bv, out = g*O+post.
// Grid 1024 = 4b x 256 i-tiles(16); 256 thr = 4 waves (each 4 c-out tiles).
// ---------------------------------------------------------------------------
__global__ __launch_bounds__(256) void combine(
    const unsigned short* __restrict__ Opart, const float* __restrict__ Lpart,
    const unsigned short* __restrict__ WvBf, const float* __restrict__ bv,
    const float* __restrict__ post, const float* __restrict__ gamma,
    float* __restrict__ out)
{
  __shared__ __align__(16) unsigned short sU[16 * 264];
  __shared__ float sL[16];

  const int tid = threadIdx.x;
  const int lane = tid & 63, w = tid >> 6;
  const int quad = lane >> 4, n16 = lane & 15;
  const int b = blockIdx.x >> 8;
  const int i0 = (blockIdx.x & 255) << 4;

  if (tid < 16) {
    float l = 0.f;
#pragma unroll
    for (int js = 0; js < 4; js++) l += Lpart[(size_t)(js * 4 + b) * Nn + i0 + tid];
    sL[tid] = 1.f / l;
  }
  __syncthreads();

#pragma unroll
  for (int pass = 0; pass < 2; pass++) {
    const int s = tid + pass * 256;        // 512 slots = 16 i x 32 c-octets
    const int il = s >> 5, c8 = (s & 31) << 3;
    const float inv = sL[il];
    float a[8] = {0.f, 0.f, 0.f, 0.f, 0.f, 0.f, 0.f, 0.f};
#pragma unroll
    for (int js = 0; js < 4; js++) {
      uint4 uu = *(const uint4*)(Opart + ((size_t)(js * 4 + b) * Nn + i0 + il) * 256 + c8);
      const unsigned short* us = (const unsigned short*)&uu;
#pragma unroll
      for (int e = 0; e < 8; e++) a[e] += bf2f(us[e]);
    }
    union { unsigned int u2[4]; uint4 u; } pk;
#pragma unroll
    for (int e2 = 0; e2 < 4; e2++) pk.u2[e2] = pk2(a[2 * e2] * inv, a[2 * e2 + 1] * inv);
    *(uint4*)&sU[il * 264 + c8] = pk.u;
  }
  __syncthreads();

  bf16x8 ub[8];
#pragma unroll
  for (int kc = 0; kc < 8; kc++)
    ub[kc] = ldfrag(&sU[n16 * 264 + kc * 32 + quad * 8]);

  const float g = gamma[0];
  const f32x4 zz = {0.f, 0.f, 0.f, 0.f};
#pragma unroll
  for (int e = 0; e < 4; e++) {
    const int ct2 = w * 4 + e;
    f32x4 o = zz;
#pragma unroll
    for (int kc = 0; kc < 8; kc++) {
      bf16x8 awv = ldfrag(WvBf + (size_t)(ct2 * 16 + n16) * Cn + kc * 32 + quad * 8);
      o = __builtin_amdgcn_mfma_f32_16x16x32_bf16(awv, ub[kc], o, 0, 0, 0);
    }
#pragma unroll
    for (int r = 0; r < 4; r++) {
      const int c = ct2 * 16 + quad * 4 + r;
      const size_t addr = ((size_t)b * Cn + c) * Nn + i0 + n16;
      out[addr] = g * (o[r] + bv[c]) + post[addr];
    }
  }
}

extern "C" void kernel_launch(void* const* d_in, const int* in_sizes, int n_in,
                              void* d_out, int out_size, void* d_ws, size_t ws_size,
                              hipStream_t stream) {
  const float* pre   = (const float*)d_in[0];
  const float* post  = (const float*)d_in[1];
  const float* Wq    = (const float*)d_in[2];
  const float* bq    = (const float*)d_in[3];
  const float* Wk    = (const float*)d_in[4];
  const float* bk    = (const float*)d_in[5];
  const float* Wv    = (const float*)d_in[6];
  const float* bv    = (const float*)d_in[7];
  const float* gamma = (const float*)d_in[8];
  float* out = (float*)d_out;

  unsigned short* ws = (unsigned short*)d_ws;
  unsigned short* Qt    = ws;                                   // 512K sh
  unsigned short* Kt    = Qt + (size_t)Bn * Nn * Dn;            // 512K sh
  unsigned short* preBf = Kt + (size_t)Bn * Nn * Dn;            // 4M sh
  unsigned short* WvBf  = preBf + (size_t)Bn * Cn * Nn;         // 64K sh
  float* Lpart = (float*)(WvBf + Cn * Cn);                      // 64K fl
  unsigned short* Opart = (unsigned short*)(Lpart + 4 * Bn * Nn);  // 16.7M sh

  qkprep<<<1032, 256, 0, stream>>>(pre, post, Wq, bq, Wk, bk, Wv,
                                   Qt, Kt, preBf, WvBf);
  flash_attn<<<1024, 256, 0, stream>>>(Qt, Kt, preBf, Opart, Lpart);
  combine<<<1024, 256, 0, stream>>>(Opart, Lpart, WvBf, bv, post, gamma, out);
}